// Round 1
// baseline (219.717 us; speedup 1.0000x reference)
//
#include <hip/hip_runtime.h>
#include <hip/hip_bf16.h>

typedef __bf16 bf16_t;
typedef bf16_t bf16x8 __attribute__((ext_vector_type(8)));
typedef float f32x4 __attribute__((ext_vector_type(4)));

#define NB 2
#define SEQ 2048
#define DIM 1024
#define NH 32
#define HDIM 32

#define LDA 40  // attn LDS pad stride

static __device__ __forceinline__ f32x4 mfma16(bf16x8 a, bf16x8 b, f32x4 c) {
    return __builtin_amdgcn_mfma_f32_16x16x32_bf16(a, b, c, 0, 0, 0);
}

// raw v_exp_f32: computes 2^x. log2(e) is pre-folded into the Q scale.
static __device__ __forceinline__ float fexp2(float x) {
    float r;
    asm("v_exp_f32 %0, %1" : "=v"(r) : "v"(x));
    return r;
}

// async global->LDS, 16B per lane; lds dest = wave-uniform base + lane*16
static __device__ __forceinline__ void load_lds16(const bf16_t* g, bf16_t* l) {
    __builtin_amdgcn_global_load_lds(
        (const __attribute__((address_space(1))) void*)(g),
        (__attribute__((address_space(3))) void*)(l), 16, 0, 0);
}

// ---------------------------------------------------------------------------
// fp32 -> bf16 convert. 5 regions (x, wq, wk, wv, wo), grid-stride.
// ---------------------------------------------------------------------------
__global__ __launch_bounds__(256)
void cvt_f32_bf16(const float* __restrict__ s0, bf16_t* __restrict__ d0, int n0,
                  const float* __restrict__ s1, bf16_t* __restrict__ d1, int n1,
                  const float* __restrict__ s2, bf16_t* __restrict__ d2, int n2,
                  const float* __restrict__ s3, bf16_t* __restrict__ d3, int n3,
                  const float* __restrict__ s4, bf16_t* __restrict__ d4, int n4) {
    const int stride = gridDim.x * blockDim.x;
    const int tid = blockIdx.x * blockDim.x + threadIdx.x;
    const float* src[5] = {s0, s1, s2, s3, s4};
    bf16_t* dst[5] = {d0, d1, d2, d3, d4};
    const int n[5] = {n0, n1, n2, n3, n4};
#pragma unroll
    for (int r = 0; r < 5; r++) {
        const int nv = n[r] >> 2;
        for (int i = tid; i < nv; i += stride) {
            float4 v = ((const float4*)src[r])[i];
            bf16_t o[4] = {(bf16_t)v.x, (bf16_t)v.y, (bf16_t)v.z, (bf16_t)v.w};
            *(uint2*)(dst[r] + i * 4) = *(const uint2*)o;
        }
    }
}

// ---------------------------------------------------------------------------
// Pipelined GEMM: C = A @ W^T, all-bf16, BN=128, BK=32, double-buffered LDS
// with RAW s_barrier + fine vmcnt (prefetch stays in flight across the
// barrier). EPI 0 (BM=64): out-proj -> fp32 C. EPI 1 (BM=128): fused QKV:
//   seg0 -> qb PRE-SCALED by slen[s]*ss[h]*log2(e)/sqrt(32) (folded SSMax
//   + exp2 base conversion), seg1 -> kb, seg2 -> vtb (transposed store).
// XCD-swizzled 1-D grid (id&7 = XCD).
// ---------------------------------------------------------------------------
template <int EPI, int BM>
__global__ __launch_bounds__(256)
void gemm_pipe(const bf16_t* __restrict__ A, const bf16_t* __restrict__ W,
               float* __restrict__ Cf, bf16_t* __restrict__ qb,
               bf16_t* __restrict__ kb, bf16_t* __restrict__ vtb,
               const float* __restrict__ slen, const float* __restrict__ ss) {
    constexpr int MI = BM / 32;  // m-frags per wave
    __shared__ alignas(16) bf16_t As[2 * BM * 32];
    __shared__ alignas(16) bf16_t Bs[2 * 128 * 32];
    const int t = threadIdx.x;
    const int lane = t & 63, wave = t >> 6;
    const int lane16 = lane & 15, quad = lane >> 4;
    const int wm = (wave >> 1) * (BM / 2), wn = (wave & 1) * 64;
    const int id = blockIdx.x;
    int m0, n0g;
    if (EPI == 1) {  // 768 = 8 xcd * 4 mslot * 24 n
        const int xcd = id & 7, slot = id >> 3;
        m0 = (xcd + 8 * (slot & 3)) * 128;
        n0g = (slot >> 2) * 128;
    } else {  // 512 = 8 xcd * 8 mslot * 8 n
        const int xcd = id & 7, slot = id >> 3;
        m0 = (xcd + 8 * (slot & 7)) * 64;
        n0g = (slot >> 3) * 128;
    }
    const int tr = t >> 2;        // 0..63
    const int tc = (t & 3) * 8;   // 0,8,16,24
    const bf16_t* ga = A + (m0 + tr) * DIM + tc;
    const bf16_t* gb = W + (n0g + tr) * DIM + tc;
    const bool vseg = (EPI == 1) && (n0g >= 2048);

    f32x4 acc[MI][4];
#pragma unroll
    for (int i = 0; i < MI; i++)
#pragma unroll
        for (int j = 0; j < 4; j++) acc[i][j] = f32x4{0.f, 0.f, 0.f, 0.f};

    auto stage = [&](int k0, int buf) {
        bf16_t* a_dst = As + buf * (BM * 32) + (t & 192) * 8;
        bf16_t* b_dst = Bs + buf * 4096 + (t & 192) * 8;
        load_lds16(ga + k0, a_dst);
        if (BM == 128) load_lds16(ga + 64 * DIM + k0, a_dst + 2048);
        load_lds16(gb + k0, b_dst);
        load_lds16(gb + 64 * DIM + k0, b_dst + 2048);
    };
    auto compute = [&](int buf) {
        bf16x8 af[MI], bfr[4];
#pragma unroll
        for (int mi = 0; mi < MI; mi++)
            af[mi] = *(const bf16x8*)(As + buf * (BM * 32) +
                                      (wm + mi * 16 + lane16) * 32 + quad * 8);
#pragma unroll
        for (int ni = 0; ni < 4; ni++)
            bfr[ni] = *(const bf16x8*)(Bs + buf * 4096 +
                                       (wn + ni * 16 + lane16) * 32 + quad * 8);
        if (vseg) {
#pragma unroll
            for (int mi = 0; mi < MI; mi++)
#pragma unroll
                for (int ni = 0; ni < 4; ni++)
                    acc[mi][ni] = mfma16(bfr[ni], af[mi], acc[mi][ni]);
        } else {
#pragma unroll
            for (int mi = 0; mi < MI; mi++)
#pragma unroll
                for (int ni = 0; ni < 4; ni++)
                    acc[mi][ni] = mfma16(af[mi], bfr[ni], acc[mi][ni]);
        }
    };

    stage(0, 0);
#pragma unroll
    for (int k0 = 0; k0 < DIM; k0 += 32) {
        const int cur = (k0 >> 5) & 1;
        if (k0 + 32 < DIM) {
            stage(k0 + 32, cur ^ 1);
            // wait only the CURRENT buffer's loads; prefetch stays in flight
            if (BM == 128)
                asm volatile("s_waitcnt vmcnt(4)" ::: "memory");
            else
                asm volatile("s_waitcnt vmcnt(3)" ::: "memory");
        } else {
            asm volatile("s_waitcnt vmcnt(0)" ::: "memory");
        }
        asm volatile("s_barrier" ::: "memory");
        compute(cur);
        if (k0 + 32 < DIM) {
            asm volatile("s_waitcnt lgkmcnt(0)" ::: "memory");
            asm volatile("s_barrier" ::: "memory");  // reads done; safe to overwrite
        }
    }

    if (EPI == 0) {
#pragma unroll
        for (int mi = 0; mi < MI; mi++)
#pragma unroll
            for (int ni = 0; ni < 4; ni++)
#pragma unroll
                for (int r = 0; r < 4; r++) {
                    int row = m0 + wm + mi * 16 + quad * 4 + r;
                    int col = n0g + wn + ni * 16 + lane16;
                    Cf[row * DIM + col] = acc[mi][ni][r];
                }
    } else if (!vseg) {
        const bool isq = (n0g < 1024);
        bf16_t* dst = isq ? qb : kb;
        const int nb = n0g & 1023;
#pragma unroll
        for (int mi = 0; mi < MI; mi++)
#pragma unroll
            for (int ni = 0; ni < 4; ni++) {
                const int h = ((nb + wn) >> 5) + (ni >> 1);  // lane-uniform
                // 1/sqrt(32) * log2(e): attn uses v_exp_f32 (2^x) directly
                const float hscale =
                    isq ? ss[h] * (0.17677669529663687f * 1.4426950408889634f)
                        : 0.f;
#pragma unroll
                for (int r = 0; r < 4; r++) {
                    int m = m0 + wm + mi * 16 + quad * 4 + r;  // b*SEQ+s
                    int nl = nb + wn + ni * 16 + lane16;       // h*HDIM+hd
                    int b = m >> 11, s = m & (SEQ - 1);
                    int d = nl & 31;
                    float v = acc[mi][ni][r];
                    if (isq) v *= slen[s] * hscale;  // folded SSMax scale
                    dst[(((b * NH + h) << 11) + s) * 32 + d] = (bf16_t)v;
                }
            }
    } else {  // V: acc = C^T tile; row(quad,r)=n(hd), col(lane16)=m(s)
        const int nb = n0g & 1023;
#pragma unroll
        for (int mi = 0; mi < MI; mi++)
#pragma unroll
            for (int ni = 0; ni < 4; ni++)
#pragma unroll
                for (int r = 0; r < 4; r++) {
                    int nl = nb + wn + ni * 16 + quad * 4 + r;  // h*HDIM+hd
                    int m = m0 + wm + mi * 16 + lane16;         // b*SEQ+s
                    int b = m >> 11, s = m & (SEQ - 1);
                    int h = nl >> 5, d = nl & 31;
                    vtb[(((b * NH + h) << 5) + d) * SEQ + s] = (bf16_t)acc[mi][ni][r];
                }
    }
}

// ---------------------------------------------------------------------------
// Flash attention, causal, SSMax+log2e PRE-FOLDED INTO Q (v_exp_f32 = 2^x).
// No online max (scores bounded; p,l share the implicit e^m factor).
// 2-WAY KV-SPLIT: each q-tile is owned by a PAIR of waves -- helper
// (whalf=1) does kv blocks [0,nh), finisher (whalf=0) does [nh,qt] incl.
// the masked diagonal; partials (o,l) merged through LDS (pure sums --
// valid because there is no online max). Blocks pair ADJACENT qt sizes
// (63,62 | 61,60 | ...) so all 4 waves in a block do equal work, and big
// blocks dispatch first (no tail). 2048 blocks -> up to 28 waves/CU.
// ---------------------------------------------------------------------------
__global__ __launch_bounds__(256)
void attn_fwd(const bf16_t* __restrict__ q, const bf16_t* __restrict__ k,
              const bf16_t* __restrict__ vt, bf16_t* __restrict__ out) {
    __shared__ alignas(16) bf16_t pscr[4][32 * LDA];
    __shared__ float comb[2][64][25];  // pad 25: conflict-free merge
    const int t = threadIdx.x;
    const int lane = t & 63, wave = t >> 6;
    const int lane16 = lane & 15, quad = lane >> 4;
    const int pairid = wave >> 1;  // 0,1: which q-tile of this block
    const int whalf = wave & 1;    // 0=finisher (diag+merge), 1=helper
    const int s0i = blockIdx.x >> 6;          // 0..31, big tiles first
    const int bh = blockIdx.x & 63;
    const int h = bh & (NH - 1), b = bh >> 5;
    const int qt = 63 - 2 * s0i - pairid;     // adjacent sizes in a block
    const int q0 = qt * 32;
    const bf16_t* qh = q + (b * NH + h) * SEQ * HDIM;
    const bf16_t* kh = k + (b * NH + h) * SEQ * HDIM;
    const bf16_t* vth = vt + (b * NH + h) * HDIM * SEQ;
    bf16_t* psw = pscr[wave];

    bf16x8 qf[2];
    qf[0] = *(const bf16x8*)(qh + (q0 + lane16) * HDIM + quad * 8);
    qf[1] = *(const bf16x8*)(qh + (q0 + 16 + lane16) * HDIM + quad * 8);

    f32x4 o[2][2];
    float lrow[2][4];
#pragma unroll
    for (int mi = 0; mi < 2; mi++)
#pragma unroll
        for (int r = 0; r < 4; r++) lrow[mi][r] = 0.f;
#pragma unroll
    for (int mi = 0; mi < 2; mi++)
#pragma unroll
        for (int ni = 0; ni < 2; ni++) o[mi][ni] = f32x4{0.f, 0.f, 0.f, 0.f};

    const bf16_t* kp0 = kh + (2 * lane16) * HDIM + quad * 8;
    const bf16_t* vp0 = vth + lane16 * SEQ + quad * 8;
    const bf16_t* vp1 = vth + (16 + lane16) * SEQ + quad * 8;

    auto process = [&](bf16x8 kf0, bf16x8 kf1, int kv, bool domask) {
        const f32x4 zz = f32x4{0.f, 0.f, 0.f, 0.f};
        f32x4 sc[2][2];
        __builtin_amdgcn_s_setprio(1);
        sc[0][0] = mfma16(qf[0], kf0, zz);
        sc[0][1] = mfma16(qf[0], kf1, zz);
        sc[1][0] = mfma16(qf[1], kf0, zz);
        sc[1][1] = mfma16(qf[1], kf1, zz);
        __builtin_amdgcn_s_setprio(0);
        bf16x8 vf0 = *(const bf16x8*)(vp0 + kv);
        bf16x8 vf1 = *(const bf16x8*)(vp1 + kv);
#pragma unroll
        for (int mi = 0; mi < 2; mi++)
#pragma unroll
            for (int r = 0; r < 4; r++) {
                float p0 = fexp2(sc[mi][0][r]);  // key kv+2*l16 (pre-scaled)
                float p1 = fexp2(sc[mi][1][r]);  // key kv+2*l16+1
                if (domask) {
                    const int rowloc = mi * 16 + quad * 4 + r;
                    if (2 * lane16 > rowloc) p0 = 0.f;
                    if (2 * lane16 + 1 > rowloc) p1 = 0.f;
                }
                lrow[mi][r] += p0 + p1;
                bf16_t pb[2] = {(bf16_t)p0, (bf16_t)p1};
                *(unsigned int*)(psw + (mi * 16 + quad * 4 + r) * LDA +
                                 2 * lane16) = *(const unsigned int*)pb;
            }
        asm volatile("s_waitcnt lgkmcnt(0)" ::: "memory");
        bf16x8 pf0 = *(const bf16x8*)(psw + lane16 * LDA + quad * 8);
        bf16x8 pf1 = *(const bf16x8*)(psw + (16 + lane16) * LDA + quad * 8);
        __builtin_amdgcn_s_setprio(1);
        o[0][0] = mfma16(pf0, vf0, o[0][0]);
        o[0][1] = mfma16(pf0, vf1, o[0][1]);
        o[1][0] = mfma16(pf1, vf0, o[1][0]);
        o[1][1] = mfma16(pf1, vf1, o[1][1]);
        __builtin_amdgcn_s_setprio(0);
    };

    // kv-split: helper [0, nh), finisher [nh, qt] (last = masked diagonal)
    const int nh = (qt + 1) >> 1;
    const int kvb = whalf ? 0 : nh * 32;
    const int kve = whalf ? nh * 32 - 32 : q0;  // inclusive last block
    if (kve >= kvb) {
        bf16x8 kc0 = *(const bf16x8*)(kp0 + kvb * HDIM);
        bf16x8 kc1 = *(const bf16x8*)(kp0 + kvb * HDIM + HDIM);
        for (int kv = kvb; kv < kve; kv += 32) {
            bf16x8 kn0 = *(const bf16x8*)(kp0 + (kv + 32) * HDIM);
            bf16x8 kn1 = *(const bf16x8*)(kp0 + (kv + 32) * HDIM + HDIM);
            process(kc0, kc1, kv, false);
            kc0 = kn0;
            kc1 = kn1;
        }
        process(kc0, kc1, kve, kve == q0);
    }

    // merge helper partials into finisher (pure sums: shared implicit scale)
    if (whalf) {
        float* c = comb[pairid][lane];
#pragma unroll
        for (int mi = 0; mi < 2; mi++)
#pragma unroll
            for (int ni = 0; ni < 2; ni++)
#pragma unroll
                for (int r = 0; r < 4; r++)
                    c[(mi * 2 + ni) * 4 + r] = o[mi][ni][r];
#pragma unroll
        for (int mi = 0; mi < 2; mi++)
#pragma unroll
            for (int r = 0; r < 4; r++) c[16 + mi * 4 + r] = lrow[mi][r];
    }
    __syncthreads();
    if (whalf) return;
    {
        const float* c = comb[pairid][lane];
#pragma unroll
        for (int mi = 0; mi < 2; mi++)
#pragma unroll
            for (int ni = 0; ni < 2; ni++)
#pragma unroll
                for (int r = 0; r < 4; r++)
                    o[mi][ni][r] += c[(mi * 2 + ni) * 4 + r];
#pragma unroll
        for (int mi = 0; mi < 2; mi++)
#pragma unroll
            for (int r = 0; r < 4; r++) lrow[mi][r] += c[16 + mi * 4 + r];
    }

#pragma unroll
    for (int mi = 0; mi < 2; mi++)
#pragma unroll
        for (int r = 0; r < 4; r++) {
            float l = lrow[mi][r];
#pragma unroll
            for (int off = 1; off < 16; off <<= 1) l += __shfl_xor(l, off);
            float inv = 1.0f / l;
            int qi = q0 + mi * 16 + quad * 4 + r;
            bf16_t* ob = out + (b * SEQ + qi) * DIM + h * HDIM;
#pragma unroll
            for (int ni = 0; ni < 2; ni++)
                ob[ni * 16 + lane16] = (bf16_t)(o[mi][ni][r] * inv);
        }
}

extern "C" void kernel_launch(void* const* d_in, const int* in_sizes, int n_in,
                              void* d_out, int out_size, void* d_ws, size_t ws_size,
                              hipStream_t stream) {
    // input order: x, mask, section_log_len, wq, wk, wv, wo, seq_scale
    // dtype model (verified): fp32 I/O, bf16 internal compute.
    const float* x = (const float*)d_in[0];
    const float* slen = (const float*)d_in[2];
    const float* wq = (const float*)d_in[3];
    const float* wk = (const float*)d_in[4];
    const float* wv = (const float*)d_in[5];
    const float* wo = (const float*)d_in[6];
    const float* ss = (const float*)d_in[7];

    const size_t ELEMS = (size_t)NB * SEQ * DIM;  // 4 Mi elems
    const size_t WELEMS = (size_t)DIM * DIM;      // 1 Mi elems
    // ws layout (bf16 elems), 32 MB (>=41 MB available per R3):
    bf16_t* xb = (bf16_t*)d_ws;           // phase 1: bf16 x
    bf16_t* abuf = xb;                    // phase 2: attn out
    bf16_t* wqkvb = xb + ELEMS;           // packed [wq;wk;wv], N=3072
    bf16_t* wob = wqkvb + 3 * WELEMS;
    bf16_t* qbuf = wob + WELEMS;          // (B,H,S,HD), PRE-SCALED (incl log2e)
    bf16_t* vtbuf = qbuf + ELEMS;         // (B,H,HD,S)
    bf16_t* kbuf = (bf16_t*)d_out;        // 8 MB of 16 MB fp32 out (scratch)

    dim3 blk(256);
    cvt_f32_bf16<<<dim3(1024), blk, 0, stream>>>(
        x, xb, (int)ELEMS, wq, wqkvb, (int)WELEMS, wk, wqkvb + WELEMS,
        (int)WELEMS, wv, wqkvb + 2 * WELEMS, (int)WELEMS, wo, wob, (int)WELEMS);

    // QKV: 768 blocks (3/CU), XCD-swizzled, pipelined K-loop
    gemm_pipe<1, 128><<<dim3(768), blk, 0, stream>>>(
        xb, wqkvb, nullptr, qbuf, kbuf, vtbuf, slen, ss);
    // attn: 2048 blocks, 2 waves per q-tile (kv-split), adjacent-size pairing
    attn_fwd<<<dim3(NB * NH * (SEQ / 32) / 2), blk, 0, stream>>>(
        qbuf, kbuf, vtbuf, abuf);
    // out-proj: 512 blocks (2/CU), XCD-swizzled, pipelined K-loop
    gemm_pipe<0, 64><<<dim3(512), blk, 0, stream>>>(
        abuf, wob, (float*)d_out, nullptr, nullptr, nullptr, nullptr, nullptr);
}

// Round 2
// 214.380 us; speedup vs baseline: 1.0249x; 1.0249x over previous
//
#include <hip/hip_runtime.h>
#include <hip/hip_bf16.h>

typedef __bf16 bf16_t;
typedef bf16_t bf16x8 __attribute__((ext_vector_type(8)));
typedef float f32x4 __attribute__((ext_vector_type(4)));

#define NB 2
#define SEQ 2048
#define DIM 1024
#define NH 32
#define HDIM 32

#define LDA 40  // attn LDS pad stride

static __device__ __forceinline__ f32x4 mfma16(bf16x8 a, bf16x8 b, f32x4 c) {
    return __builtin_amdgcn_mfma_f32_16x16x32_bf16(a, b, c, 0, 0, 0);
}

// raw v_exp_f32: computes 2^x. log2(e) is pre-folded into the Q scale.
static __device__ __forceinline__ float fexp2(float x) {
    float r;
    asm("v_exp_f32 %0, %1" : "=v"(r) : "v"(x));
    return r;
}

// async global->LDS, 16B per lane; lds dest = wave-uniform base + lane*16
static __device__ __forceinline__ void load_lds16(const bf16_t* g, bf16_t* l) {
    __builtin_amdgcn_global_load_lds(
        (const __attribute__((address_space(1))) void*)(g),
        (__attribute__((address_space(3))) void*)(l), 16, 0, 0);
}

// ---------------------------------------------------------------------------
// fp32 -> bf16 convert. 5 regions (x, wq, wk, wv, wo), grid-stride.
// ---------------------------------------------------------------------------
__global__ __launch_bounds__(256)
void cvt_f32_bf16(const float* __restrict__ s0, bf16_t* __restrict__ d0, int n0,
                  const float* __restrict__ s1, bf16_t* __restrict__ d1, int n1,
                  const float* __restrict__ s2, bf16_t* __restrict__ d2, int n2,
                  const float* __restrict__ s3, bf16_t* __restrict__ d3, int n3,
                  const float* __restrict__ s4, bf16_t* __restrict__ d4, int n4) {
    const int stride = gridDim.x * blockDim.x;
    const int tid = blockIdx.x * blockDim.x + threadIdx.x;
    const float* src[5] = {s0, s1, s2, s3, s4};
    bf16_t* dst[5] = {d0, d1, d2, d3, d4};
    const int n[5] = {n0, n1, n2, n3, n4};
#pragma unroll
    for (int r = 0; r < 5; r++) {
        const int nv = n[r] >> 2;
        for (int i = tid; i < nv; i += stride) {
            float4 v = ((const float4*)src[r])[i];
            bf16_t o[4] = {(bf16_t)v.x, (bf16_t)v.y, (bf16_t)v.z, (bf16_t)v.w};
            *(uint2*)(dst[r] + i * 4) = *(const uint2*)o;
        }
    }
}

// ---------------------------------------------------------------------------
// Pipelined GEMM: C = A @ W^T, all-bf16, BN=128, BK=32, double-buffered LDS
// with RAW s_barrier + fine vmcnt (prefetch stays in flight across the
// barrier). EPI 0 (BM=64): out-proj -> fp32 C. EPI 1 (BM=128): fused QKV:
//   seg0 -> qb PRE-SCALED by slen[s]*ss[h]*log2(e)/sqrt(32) (folded SSMax
//   + exp2 base conversion), seg1 -> kb, seg2 -> vtb (transposed store).
// XCD-swizzled 1-D grid (id&7 = XCD).
// ---------------------------------------------------------------------------
template <int EPI, int BM>
__global__ __launch_bounds__(256)
void gemm_pipe(const bf16_t* __restrict__ A, const bf16_t* __restrict__ W,
               float* __restrict__ Cf, bf16_t* __restrict__ qb,
               bf16_t* __restrict__ kb, bf16_t* __restrict__ vtb,
               const float* __restrict__ slen, const float* __restrict__ ss) {
    constexpr int MI = BM / 32;  // m-frags per wave
    __shared__ alignas(16) bf16_t As[2 * BM * 32];
    __shared__ alignas(16) bf16_t Bs[2 * 128 * 32];
    const int t = threadIdx.x;
    const int lane = t & 63, wave = t >> 6;
    const int lane16 = lane & 15, quad = lane >> 4;
    const int wm = (wave >> 1) * (BM / 2), wn = (wave & 1) * 64;
    const int id = blockIdx.x;
    int m0, n0g;
    if (EPI == 1) {  // 768 = 8 xcd * 4 mslot * 24 n
        const int xcd = id & 7, slot = id >> 3;
        m0 = (xcd + 8 * (slot & 3)) * 128;
        n0g = (slot >> 2) * 128;
    } else {  // 512 = 8 xcd * 8 mslot * 8 n
        const int xcd = id & 7, slot = id >> 3;
        m0 = (xcd + 8 * (slot & 7)) * 64;
        n0g = (slot >> 3) * 128;
    }
    const int tr = t >> 2;        // 0..63
    const int tc = (t & 3) * 8;   // 0,8,16,24
    const bf16_t* ga = A + (m0 + tr) * DIM + tc;
    const bf16_t* gb = W + (n0g + tr) * DIM + tc;
    const bool vseg = (EPI == 1) && (n0g >= 2048);

    f32x4 acc[MI][4];
#pragma unroll
    for (int i = 0; i < MI; i++)
#pragma unroll
        for (int j = 0; j < 4; j++) acc[i][j] = f32x4{0.f, 0.f, 0.f, 0.f};

    auto stage = [&](int k0, int buf) {
        bf16_t* a_dst = As + buf * (BM * 32) + (t & 192) * 8;
        bf16_t* b_dst = Bs + buf * 4096 + (t & 192) * 8;
        load_lds16(ga + k0, a_dst);
        if (BM == 128) load_lds16(ga + 64 * DIM + k0, a_dst + 2048);
        load_lds16(gb + k0, b_dst);
        load_lds16(gb + 64 * DIM + k0, b_dst + 2048);
    };
    auto compute = [&](int buf) {
        bf16x8 af[MI], bfr[4];
#pragma unroll
        for (int mi = 0; mi < MI; mi++)
            af[mi] = *(const bf16x8*)(As + buf * (BM * 32) +
                                      (wm + mi * 16 + lane16) * 32 + quad * 8);
#pragma unroll
        for (int ni = 0; ni < 4; ni++)
            bfr[ni] = *(const bf16x8*)(Bs + buf * 4096 +
                                       (wn + ni * 16 + lane16) * 32 + quad * 8);
        if (vseg) {
#pragma unroll
            for (int mi = 0; mi < MI; mi++)
#pragma unroll
                for (int ni = 0; ni < 4; ni++)
                    acc[mi][ni] = mfma16(bfr[ni], af[mi], acc[mi][ni]);
        } else {
#pragma unroll
            for (int mi = 0; mi < MI; mi++)
#pragma unroll
                for (int ni = 0; ni < 4; ni++)
                    acc[mi][ni] = mfma16(af[mi], bfr[ni], acc[mi][ni]);
        }
    };

    stage(0, 0);
#pragma unroll
    for (int k0 = 0; k0 < DIM; k0 += 32) {
        const int cur = (k0 >> 5) & 1;
        if (k0 + 32 < DIM) {
            stage(k0 + 32, cur ^ 1);
            // wait only the CURRENT buffer's loads; prefetch stays in flight
            if (BM == 128)
                asm volatile("s_waitcnt vmcnt(4)" ::: "memory");
            else
                asm volatile("s_waitcnt vmcnt(3)" ::: "memory");
        } else {
            asm volatile("s_waitcnt vmcnt(0)" ::: "memory");
        }
        asm volatile("s_barrier" ::: "memory");
        compute(cur);
        if (k0 + 32 < DIM) {
            asm volatile("s_waitcnt lgkmcnt(0)" ::: "memory");
            asm volatile("s_barrier" ::: "memory");  // reads done; safe to overwrite
        }
    }

    if (EPI == 0) {
#pragma unroll
        for (int mi = 0; mi < MI; mi++)
#pragma unroll
            for (int ni = 0; ni < 4; ni++)
#pragma unroll
                for (int r = 0; r < 4; r++) {
                    int row = m0 + wm + mi * 16 + quad * 4 + r;
                    int col = n0g + wn + ni * 16 + lane16;
                    Cf[row * DIM + col] = acc[mi][ni][r];
                }
    } else if (!vseg) {
        const bool isq = (n0g < 1024);
        bf16_t* dst = isq ? qb : kb;
        const int nb = n0g & 1023;
#pragma unroll
        for (int mi = 0; mi < MI; mi++)
#pragma unroll
            for (int ni = 0; ni < 4; ni++) {
                const int h = ((nb + wn) >> 5) + (ni >> 1);  // lane-uniform
                // 1/sqrt(32) * log2(e): attn uses v_exp_f32 (2^x) directly
                const float hscale =
                    isq ? ss[h] * (0.17677669529663687f * 1.4426950408889634f)
                        : 0.f;
#pragma unroll
                for (int r = 0; r < 4; r++) {
                    int m = m0 + wm + mi * 16 + quad * 4 + r;  // b*SEQ+s
                    int nl = nb + wn + ni * 16 + lane16;       // h*HDIM+hd
                    int b = m >> 11, s = m & (SEQ - 1);
                    int d = nl & 31;
                    float v = acc[mi][ni][r];
                    if (isq) v *= slen[s] * hscale;  // folded SSMax scale
                    dst[(((b * NH + h) << 11) + s) * 32 + d] = (bf16_t)v;
                }
            }
    } else {  // V: acc = C^T tile; row(quad,r)=n(hd), col(lane16)=m(s)
        const int nb = n0g & 1023;
#pragma unroll
        for (int mi = 0; mi < MI; mi++)
#pragma unroll
            for (int ni = 0; ni < 4; ni++)
#pragma unroll
                for (int r = 0; r < 4; r++) {
                    int nl = nb + wn + ni * 16 + quad * 4 + r;  // h*HDIM+hd
                    int m = m0 + wm + mi * 16 + lane16;         // b*SEQ+s
                    int b = m >> 11, s = m & (SEQ - 1);
                    int h = nl >> 5, d = nl & 31;
                    vtb[(((b * NH + h) << 5) + d) * SEQ + s] = (bf16_t)acc[mi][ni][r];
                }
    }
}

// ---------------------------------------------------------------------------
// Flash attention, causal, SSMax+log2e PRE-FOLDED INTO Q (v_exp_f32 = 2^x).
// No online max (scores bounded; p,l share the implicit e^m factor).
// SOFTWARE-PIPELINED P: double-buffered LDS P-tile; iter i issues ds_read of
// P(i-1) BEFORE the ds_writes of P(i) (LDS is in-order per wave), so the
// write->lgkmcnt(0)->read serial drain is gone; PV(i-1) overlaps exp(i).
// l computed by ONES-COLUMN MFMA (ol += P x 1): kills 16 VALU adds/iter and
// the epilogue shuffle reduce; l is consistent with the bf16 P used in PV.
// 1024 blocks, 1 wave per 32-row q-tile, zigzag pairing (R0 structure).
// ---------------------------------------------------------------------------
__global__ __launch_bounds__(256)
void attn_fwd(const bf16_t* __restrict__ q, const bf16_t* __restrict__ k,
              const bf16_t* __restrict__ vt, bf16_t* __restrict__ out) {
    __shared__ alignas(16) bf16_t pscr[4][2][32 * LDA];
    const int t = threadIdx.x;
    const int lane = t & 63, wave = t >> 6;
    const int lane16 = lane & 15, quad = lane >> 4;
    const int gw = blockIdx.x * 4 + wave;  // 0..4095
    const int idx = gw & 63;
    const int qt = (idx & 1) ? (63 - (idx >> 1)) : (idx >> 1);
    const int h = (gw >> 6) & (NH - 1);
    const int b = gw >> 11;
    const int q0 = qt * 32;
    const bf16_t* qh = q + (b * NH + h) * SEQ * HDIM;
    const bf16_t* kh = k + (b * NH + h) * SEQ * HDIM;
    const bf16_t* vth = vt + (b * NH + h) * HDIM * SEQ;

    // LDS bases: write row = mi*16+quad*4+r, cols 2*lane16..+1;
    // read row = lane16 (+16), cols quad*8..+7 (b128, 16B-aligned: 80*l16+16*q)
    bf16_t* wbase0 = pscr[wave][0] + quad * 4 * LDA + 2 * lane16;
    bf16_t* wbase1 = pscr[wave][1] + quad * 4 * LDA + 2 * lane16;
    const bf16_t* rbase0 = pscr[wave][0] + lane16 * LDA + quad * 8;
    const bf16_t* rbase1 = pscr[wave][1] + lane16 * LDA + quad * 8;

    bf16x8 qf[2];
    qf[0] = *(const bf16x8*)(qh + (q0 + lane16) * HDIM + quad * 8);
    qf[1] = *(const bf16x8*)(qh + (q0 + 16 + lane16) * HDIM + quad * 8);

    bf16x8 ones;
#pragma unroll
    for (int j = 0; j < 8; j++) ones[j] = (bf16_t)1.0f;

    f32x4 o[2][2], ol[2], sc[2][2];
#pragma unroll
    for (int mi = 0; mi < 2; mi++) {
        ol[mi] = f32x4{0.f, 0.f, 0.f, 0.f};
#pragma unroll
        for (int ni = 0; ni < 2; ni++) o[mi][ni] = f32x4{0.f, 0.f, 0.f, 0.f};
    }

    const bf16_t* kp0 = kh + (2 * lane16) * HDIM + quad * 8;
    const bf16_t* vp0 = vth + lane16 * SEQ + quad * 8;
    const bf16_t* vp1 = vth + (16 + lane16) * SEQ + quad * 8;

    const f32x4 zz = f32x4{0.f, 0.f, 0.f, 0.f};
    bf16x8 kc0, kc1, pf0, pf1, vprev0, vprev1;

    auto qk = [&]() {
        __builtin_amdgcn_s_setprio(1);
        sc[0][0] = mfma16(qf[0], kc0, zz);
        sc[0][1] = mfma16(qf[0], kc1, zz);
        sc[1][0] = mfma16(qf[1], kc0, zz);
        sc[1][1] = mfma16(qf[1], kc1, zz);
        __builtin_amdgcn_s_setprio(0);
    };
    auto ldp = [&](const bf16_t* rb) {
        pf0 = *(const bf16x8*)(rb);
        pf1 = *(const bf16x8*)(rb + 16 * LDA);
    };
    auto expw = [&](bf16_t* wb, bool domask) {
#pragma unroll
        for (int mi = 0; mi < 2; mi++)
#pragma unroll
            for (int r = 0; r < 4; r++) {
                float p0 = fexp2(sc[mi][0][r]);  // key kv+2*l16 (pre-scaled)
                float p1 = fexp2(sc[mi][1][r]);  // key kv+2*l16+1
                if (domask) {
                    const int rowloc = mi * 16 + quad * 4 + r;
                    if (2 * lane16 > rowloc) p0 = 0.f;
                    if (2 * lane16 + 1 > rowloc) p1 = 0.f;
                }
                bf16_t pb[2] = {(bf16_t)p0, (bf16_t)p1};
                *(unsigned int*)(wb + (mi * 16 + r) * LDA) =
                    *(const unsigned int*)pb;
            }
    };
    auto pv = [&]() {
        __builtin_amdgcn_s_setprio(1);
        o[0][0] = mfma16(pf0, vprev0, o[0][0]);
        o[0][1] = mfma16(pf0, vprev1, o[0][1]);
        o[1][0] = mfma16(pf1, vprev0, o[1][0]);
        o[1][1] = mfma16(pf1, vprev1, o[1][1]);
        ol[0] = mfma16(pf0, ones, ol[0]);
        ol[1] = mfma16(pf1, ones, ol[1]);
        __builtin_amdgcn_s_setprio(0);
    };

    const int nb = qt + 1;  // kv blocks (last = masked diagonal)

    // ---- iter 0: QK+exp+write buf0; V0 kept in regs; prefetch K1
    kc0 = *(const bf16x8*)(kp0);
    kc1 = *(const bf16x8*)(kp0 + HDIM);
    qk();
    vprev0 = *(const bf16x8*)(vp0);
    vprev1 = *(const bf16x8*)(vp1);
    if (nb > 1) {
        kc0 = *(const bf16x8*)(kp0 + 32 * HDIM);
        kc1 = *(const bf16x8*)(kp0 + 32 * HDIM + HDIM);
    }
    expw(wbase0, nb == 1);

    // ---- main loop i = 1..nb-2 (branch-free body)
    for (int i = 1; i < nb - 1; i++) {
        const int kv = i << 5;
        qk();  // K block i
        bf16x8 vc0 = *(const bf16x8*)(vp0 + kv);
        bf16x8 vc1 = *(const bf16x8*)(vp1 + kv);
        // branchless K prefetch (worst case reads 2KB past kbuf, inside d_out)
        bf16x8 kn0 = *(const bf16x8*)(kp0 + (kv + 32) * HDIM);
        bf16x8 kn1 = *(const bf16x8*)(kp0 + (kv + 32) * HDIM + HDIM);
        ldp(((i - 1) & 1) ? rbase1 : rbase0);  // issue BEFORE the writes
        expw((i & 1) ? wbase1 : wbase0, false);
        pv();  // P(i-1) x V(i-1), overlapped with exp(i)
        kc0 = kn0;
        kc1 = kn1;
        vprev0 = vc0;
        vprev1 = vc1;
    }

    // ---- peeled last iter (masked diagonal), nb >= 2
    if (nb > 1) {
        const int kv = (nb - 1) << 5;
        qk();  // K block nb-1 (prefetched)
        bf16x8 vc0 = *(const bf16x8*)(vp0 + kv);
        bf16x8 vc1 = *(const bf16x8*)(vp1 + kv);
        ldp(((nb - 2) & 1) ? rbase1 : rbase0);
        expw(((nb - 1) & 1) ? wbase1 : wbase0, true);
        pv();  // P(nb-2) x V(nb-2)
        vprev0 = vc0;
        vprev1 = vc1;
    }

    // ---- epilogue: last P tile
    ldp(((nb - 1) & 1) ? rbase1 : rbase0);
    pv();

    // ---- normalize + store: l = ol[mi][r] (replicated across lane16)
#pragma unroll
    for (int mi = 0; mi < 2; mi++)
#pragma unroll
        for (int r = 0; r < 4; r++) {
            float inv = 1.0f / ol[mi][r];
            int qi = q0 + mi * 16 + quad * 4 + r;
            bf16_t* ob = out + (b * SEQ + qi) * DIM + h * HDIM;
            ob[lane16] = (bf16_t)(o[mi][0][r] * inv);
            ob[16 + lane16] = (bf16_t)(o[mi][1][r] * inv);
        }
}

extern "C" void kernel_launch(void* const* d_in, const int* in_sizes, int n_in,
                              void* d_out, int out_size, void* d_ws, size_t ws_size,
                              hipStream_t stream) {
    // input order: x, mask, section_log_len, wq, wk, wv, wo, seq_scale
    // dtype model (verified): fp32 I/O, bf16 internal compute.
    const float* x = (const float*)d_in[0];
    const float* slen = (const float*)d_in[2];
    const float* wq = (const float*)d_in[3];
    const float* wk = (const float*)d_in[4];
    const float* wv = (const float*)d_in[5];
    const float* wo = (const float*)d_in[6];
    const float* ss = (const float*)d_in[7];

    const size_t ELEMS = (size_t)NB * SEQ * DIM;  // 4 Mi elems
    const size_t WELEMS = (size_t)DIM * DIM;      // 1 Mi elems
    // ws layout (bf16 elems), 32 MB:
    bf16_t* xb = (bf16_t*)d_ws;           // phase 1: bf16 x
    bf16_t* abuf = xb;                    // phase 2: attn out
    bf16_t* wqkvb = xb + ELEMS;           // packed [wq;wk;wv], N=3072
    bf16_t* wob = wqkvb + 3 * WELEMS;
    bf16_t* qbuf = wob + WELEMS;          // (B,H,S,HD), PRE-SCALED (incl log2e)
    bf16_t* vtbuf = qbuf + ELEMS;         // (B,H,HD,S)
    bf16_t* kbuf = (bf16_t*)d_out;        // 8 MB of 16 MB fp32 out (scratch)

    dim3 blk(256);
    cvt_f32_bf16<<<dim3(1024), blk, 0, stream>>>(
        x, xb, (int)ELEMS, wq, wqkvb, (int)WELEMS, wk, wqkvb + WELEMS,
        (int)WELEMS, wv, wqkvb + 2 * WELEMS, (int)WELEMS, wo, wob, (int)WELEMS);

    // QKV: 768 blocks (3/CU), XCD-swizzled, pipelined K-loop
    gemm_pipe<1, 128><<<dim3(768), blk, 0, stream>>>(
        xb, wqkvb, nullptr, qbuf, kbuf, vtbuf, slen, ss);
    // attn: 1024 blocks, 1 wave per q-tile, software-pipelined P
    attn_fwd<<<dim3(NB * NH * (SEQ / 32) / 4), blk, 0, stream>>>(
        qbuf, kbuf, vtbuf, abuf);
    // out-proj: 512 blocks (2/CU), XCD-swizzled, pipelined K-loop
    gemm_pipe<0, 64><<<dim3(512), blk, 0, stream>>>(
        abuf, wob, (float*)d_out, nullptr, nullptr, nullptr, nullptr, nullptr);
}

// Round 3
// 209.568 us; speedup vs baseline: 1.0484x; 1.0230x over previous
//
#include <hip/hip_runtime.h>
#include <hip/hip_bf16.h>

typedef __bf16 bf16_t;
typedef bf16_t bf16x8 __attribute__((ext_vector_type(8)));
typedef float f32x4 __attribute__((ext_vector_type(4)));

#define NB 2
#define SEQ 2048
#define DIM 1024
#define NH 32
#define HDIM 32

#define LDA 40  // attn LDS pad stride

static __device__ __forceinline__ f32x4 mfma16(bf16x8 a, bf16x8 b, f32x4 c) {
    return __builtin_amdgcn_mfma_f32_16x16x32_bf16(a, b, c, 0, 0, 0);
}

// raw v_exp_f32: computes 2^x. log2(e) is pre-folded into the Q scale.
static __device__ __forceinline__ float fexp2(float x) {
    float r;
    asm("v_exp_f32 %0, %1" : "=v"(r) : "v"(x));
    return r;
}

// async global->LDS, 16B per lane; lds dest = wave-uniform base + lane*16
static __device__ __forceinline__ void load_lds16(const bf16_t* g, bf16_t* l) {
    __builtin_amdgcn_global_load_lds(
        (const __attribute__((address_space(1))) void*)(g),
        (__attribute__((address_space(3))) void*)(l), 16, 0, 0);
}

// ---------------------------------------------------------------------------
// fp32 -> bf16 convert. 5 regions (x, wq, wk, wv, wo), grid-stride.
// ---------------------------------------------------------------------------
__global__ __launch_bounds__(256)
void cvt_f32_bf16(const float* __restrict__ s0, bf16_t* __restrict__ d0, int n0,
                  const float* __restrict__ s1, bf16_t* __restrict__ d1, int n1,
                  const float* __restrict__ s2, bf16_t* __restrict__ d2, int n2,
                  const float* __restrict__ s3, bf16_t* __restrict__ d3, int n3,
                  const float* __restrict__ s4, bf16_t* __restrict__ d4, int n4) {
    const int stride = gridDim.x * blockDim.x;
    const int tid = blockIdx.x * blockDim.x + threadIdx.x;
    const float* src[5] = {s0, s1, s2, s3, s4};
    bf16_t* dst[5] = {d0, d1, d2, d3, d4};
    const int n[5] = {n0, n1, n2, n3, n4};
#pragma unroll
    for (int r = 0; r < 5; r++) {
        const int nv = n[r] >> 2;
        for (int i = tid; i < nv; i += stride) {
            float4 v = ((const float4*)src[r])[i];
            bf16_t o[4] = {(bf16_t)v.x, (bf16_t)v.y, (bf16_t)v.z, (bf16_t)v.w};
            *(uint2*)(dst[r] + i * 4) = *(const uint2*)o;
        }
    }
}

// ---------------------------------------------------------------------------
// Pipelined GEMM: C = A @ W^T, all-bf16, BN=128, BK=32.
// TRIPLE-buffered LDS (stage k+2 ahead, steady-state vmcnt(8)/(6)): loads get
// two compute phases to land instead of one. BOTH-SIDES XOR SWIZZLE
// (q' = q ^ ((row>>1)&3)): global_load_lds writes linearly, so the swizzle is
// applied to the global SOURCE address and the LDS READ address with the same
// involution. Kills the 8-way ds_read_b128 bank conflict of the row-major
// [*][32] tile (bank group (4r+q') mod 8 now covers all 8 groups 2-way=free).
// EPI 0 (BM=64): out-proj -> fp32 C. EPI 1 (BM=128): fused QKV:
//   seg0 -> qb PRE-SCALED by slen[s]*ss[h]*log2(e)/sqrt(32), seg1 -> kb,
//   seg2 -> vtb (transposed store). XCD-swizzled 1-D grid (id&7 = XCD).
// ---------------------------------------------------------------------------
template <int EPI, int BM>
__global__ __launch_bounds__(256)
void gemm_pipe(const bf16_t* __restrict__ A, const bf16_t* __restrict__ W,
               float* __restrict__ Cf, bf16_t* __restrict__ qb,
               bf16_t* __restrict__ kb, bf16_t* __restrict__ vtb,
               const float* __restrict__ slen, const float* __restrict__ ss) {
    constexpr int MI = BM / 32;      // m-frags per wave
    constexpr int ABUF = BM * 32;    // elems per A stage buffer
    __shared__ alignas(16) bf16_t As[3 * ABUF];
    __shared__ alignas(16) bf16_t Bs[3 * 4096];
    const int t = threadIdx.x;
    const int lane = t & 63, wave = t >> 6;
    const int lane16 = lane & 15, quad = lane >> 4;
    const int wm = (wave >> 1) * (BM / 2), wn = (wave & 1) * 64;
    const int id = blockIdx.x;
    int m0, n0g;
    if (EPI == 1) {  // 768 = 8 xcd * 4 mslot * 24 n
        const int xcd = id & 7, slot = id >> 3;
        m0 = (xcd + 8 * (slot & 3)) * 128;
        n0g = (slot >> 2) * 128;
    } else {  // 512 = 8 xcd * 8 mslot * 8 n
        const int xcd = id & 7, slot = id >> 3;
        m0 = (xcd + 8 * (slot & 7)) * 64;
        n0g = (slot >> 3) * 128;
    }
    const int tr = t >> 2;                        // 0..63 (LDS chunk row)
    const int tc = ((t & 3) ^ ((tr >> 1) & 3)) * 8;  // SWIZZLED source quad
    const bf16_t* ga = A + (m0 + tr) * DIM + tc;
    const bf16_t* gb = W + (n0g + tr) * DIM + tc;
    // read-side: same involution; (row>>1)&3 == (lane16>>1)&3 since wm, mi*16,
    // wn, ni*16 are all multiples of 16.
    const int rq = (quad ^ ((lane16 >> 1) & 3)) * 8;
    const bool vseg = (EPI == 1) && (n0g >= 2048);

    f32x4 acc[MI][4];
#pragma unroll
    for (int i = 0; i < MI; i++)
#pragma unroll
        for (int j = 0; j < 4; j++) acc[i][j] = f32x4{0.f, 0.f, 0.f, 0.f};

    auto stage = [&](int k0, int buf) {
        bf16_t* a_dst = As + buf * ABUF + (t & 192) * 8;
        bf16_t* b_dst = Bs + buf * 4096 + (t & 192) * 8;
        load_lds16(ga + k0, a_dst);
        if (BM == 128) load_lds16(ga + 64 * DIM + k0, a_dst + 2048);
        load_lds16(gb + k0, b_dst);
        load_lds16(gb + 64 * DIM + k0, b_dst + 2048);
    };
    auto compute = [&](int buf) {
        bf16x8 af[MI], bfr[4];
#pragma unroll
        for (int mi = 0; mi < MI; mi++)
            af[mi] = *(const bf16x8*)(As + buf * ABUF +
                                      (wm + mi * 16 + lane16) * 32 + rq);
#pragma unroll
        for (int ni = 0; ni < 4; ni++)
            bfr[ni] = *(const bf16x8*)(Bs + buf * 4096 +
                                       (wn + ni * 16 + lane16) * 32 + rq);
        if (vseg) {
#pragma unroll
            for (int mi = 0; mi < MI; mi++)
#pragma unroll
                for (int ni = 0; ni < 4; ni++)
                    acc[mi][ni] = mfma16(bfr[ni], af[mi], acc[mi][ni]);
        } else {
#pragma unroll
            for (int mi = 0; mi < MI; mi++)
#pragma unroll
                for (int ni = 0; ni < 4; ni++)
                    acc[mi][ni] = mfma16(af[mi], bfr[ni], acc[mi][ni]);
        }
    };

    stage(0, 0);
    stage(32, 1);
#pragma unroll
    for (int k0 = 0; k0 < DIM; k0 += 32) {
        const int it = k0 >> 5;
        const int cur = it % 3;
        if (k0 + 64 < DIM) {
            stage(k0 + 64, (it + 2) % 3);
            // 2 stages in flight ahead; wait only the CURRENT buffer's loads
            if (BM == 128)
                asm volatile("s_waitcnt vmcnt(8)" ::: "memory");
            else
                asm volatile("s_waitcnt vmcnt(6)" ::: "memory");
        } else if (k0 + 32 < DIM) {
            // no more staging; 1 stage (last buffer) still in flight
            if (BM == 128)
                asm volatile("s_waitcnt vmcnt(4)" ::: "memory");
            else
                asm volatile("s_waitcnt vmcnt(3)" ::: "memory");
        } else {
            asm volatile("s_waitcnt vmcnt(0)" ::: "memory");
        }
        asm volatile("s_barrier" ::: "memory");
        compute(cur);
        if (k0 + 32 < DIM) {
            asm volatile("s_waitcnt lgkmcnt(0)" ::: "memory");
            asm volatile("s_barrier" ::: "memory");  // reads done; safe to overwrite
        }
    }

    if (EPI == 0) {
#pragma unroll
        for (int mi = 0; mi < MI; mi++)
#pragma unroll
            for (int ni = 0; ni < 4; ni++)
#pragma unroll
                for (int r = 0; r < 4; r++) {
                    int row = m0 + wm + mi * 16 + quad * 4 + r;
                    int col = n0g + wn + ni * 16 + lane16;
                    Cf[row * DIM + col] = acc[mi][ni][r];
                }
    } else if (!vseg) {
        const bool isq = (n0g < 1024);
        bf16_t* dst = isq ? qb : kb;
        const int nb = n0g & 1023;
#pragma unroll
        for (int mi = 0; mi < MI; mi++)
#pragma unroll
            for (int ni = 0; ni < 4; ni++) {
                const int h = ((nb + wn) >> 5) + (ni >> 1);  // lane-uniform
                // 1/sqrt(32) * log2(e): attn uses v_exp_f32 (2^x) directly
                const float hscale =
                    isq ? ss[h] * (0.17677669529663687f * 1.4426950408889634f)
                        : 0.f;
#pragma unroll
                for (int r = 0; r < 4; r++) {
                    int m = m0 + wm + mi * 16 + quad * 4 + r;  // b*SEQ+s
                    int nl = nb + wn + ni * 16 + lane16;       // h*HDIM+hd
                    int b = m >> 11, s = m & (SEQ - 1);
                    int d = nl & 31;
                    float v = acc[mi][ni][r];
                    if (isq) v *= slen[s] * hscale;  // folded SSMax scale
                    dst[(((b * NH + h) << 11) + s) * 32 + d] = (bf16_t)v;
                }
            }
    } else {  // V: acc = C^T tile; row(quad,r)=n(hd), col(lane16)=m(s)
        const int nb = n0g & 1023;
#pragma unroll
        for (int mi = 0; mi < MI; mi++)
#pragma unroll
            for (int ni = 0; ni < 4; ni++)
#pragma unroll
                for (int r = 0; r < 4; r++) {
                    int nl = nb + wn + ni * 16 + quad * 4 + r;  // h*HDIM+hd
                    int m = m0 + wm + mi * 16 + lane16;         // b*SEQ+s
                    int b = m >> 11, s = m & (SEQ - 1);
                    int h = nl >> 5, d = nl & 31;
                    vtb[(((b * NH + h) << 5) + d) * SEQ + s] = (bf16_t)acc[mi][ni][r];
                }
    }
}

// ---------------------------------------------------------------------------
// Flash attention, causal, SSMax+log2e PRE-FOLDED INTO Q (v_exp_f32 = 2^x).
// No online max (scores bounded; p,l share the implicit e^m factor).
// SOFTWARE-PIPELINED P: double-buffered LDS P-tile; iter i issues ds_read of
// P(i-1) BEFORE the ds_writes of P(i) (LDS is in-order per wave), so the
// write->lgkmcnt(0)->read serial drain is gone; PV(i-1) overlaps exp(i).
// l computed by ONES-COLUMN MFMA (ol += P x 1): kills 16 VALU adds/iter and
// the epilogue shuffle reduce; l is consistent with the bf16 P used in PV.
// 1024 blocks, 1 wave per 32-row q-tile, zigzag pairing (R0 structure).
// ---------------------------------------------------------------------------
__global__ __launch_bounds__(256)
void attn_fwd(const bf16_t* __restrict__ q, const bf16_t* __restrict__ k,
              const bf16_t* __restrict__ vt, bf16_t* __restrict__ out) {
    __shared__ alignas(16) bf16_t pscr[4][2][32 * LDA];
    const int t = threadIdx.x;
    const int lane = t & 63, wave = t >> 6;
    const int lane16 = lane & 15, quad = lane >> 4;
    const int gw = blockIdx.x * 4 + wave;  // 0..4095
    const int idx = gw & 63;
    const int qt = (idx & 1) ? (63 - (idx >> 1)) : (idx >> 1);
    const int h = (gw >> 6) & (NH - 1);
    const int b = gw >> 11;
    const int q0 = qt * 32;
    const bf16_t* qh = q + (b * NH + h) * SEQ * HDIM;
    const bf16_t* kh = k + (b * NH + h) * SEQ * HDIM;
    const bf16_t* vth = vt + (b * NH + h) * HDIM * SEQ;

    // LDS bases: write row = mi*16+quad*4+r, cols 2*lane16..+1;
    // read row = lane16 (+16), cols quad*8..+7 (b128, 16B-aligned: 80*l16+16*q)
    bf16_t* wbase0 = pscr[wave][0] + quad * 4 * LDA + 2 * lane16;
    bf16_t* wbase1 = pscr[wave][1] + quad * 4 * LDA + 2 * lane16;
    const bf16_t* rbase0 = pscr[wave][0] + lane16 * LDA + quad * 8;
    const bf16_t* rbase1 = pscr[wave][1] + lane16 * LDA + quad * 8;

    bf16x8 qf[2];
    qf[0] = *(const bf16x8*)(qh + (q0 + lane16) * HDIM + quad * 8);
    qf[1] = *(const bf16x8*)(qh + (q0 + 16 + lane16) * HDIM + quad * 8);

    bf16x8 ones;
#pragma unroll
    for (int j = 0; j < 8; j++) ones[j] = (bf16_t)1.0f;

    f32x4 o[2][2], ol[2], sc[2][2];
#pragma unroll
    for (int mi = 0; mi < 2; mi++) {
        ol[mi] = f32x4{0.f, 0.f, 0.f, 0.f};
#pragma unroll
        for (int ni = 0; ni < 2; ni++) o[mi][ni] = f32x4{0.f, 0.f, 0.f, 0.f};
    }

    const bf16_t* kp0 = kh + (2 * lane16) * HDIM + quad * 8;
    const bf16_t* vp0 = vth + lane16 * SEQ + quad * 8;
    const bf16_t* vp1 = vth + (16 + lane16) * SEQ + quad * 8;

    const f32x4 zz = f32x4{0.f, 0.f, 0.f, 0.f};
    bf16x8 kc0, kc1, pf0, pf1, vprev0, vprev1;

    auto qk = [&]() {
        __builtin_amdgcn_s_setprio(1);
        sc[0][0] = mfma16(qf[0], kc0, zz);
        sc[0][1] = mfma16(qf[0], kc1, zz);
        sc[1][0] = mfma16(qf[1], kc0, zz);
        sc[1][1] = mfma16(qf[1], kc1, zz);
        __builtin_amdgcn_s_setprio(0);
    };
    auto ldp = [&](const bf16_t* rb) {
        pf0 = *(const bf16x8*)(rb);
        pf1 = *(const bf16x8*)(rb + 16 * LDA);
    };
    auto expw = [&](bf16_t* wb, bool domask) {
#pragma unroll
        for (int mi = 0; mi < 2; mi++)
#pragma unroll
            for (int r = 0; r < 4; r++) {
                float p0 = fexp2(sc[mi][0][r]);  // key kv+2*l16 (pre-scaled)
                float p1 = fexp2(sc[mi][1][r]);  // key kv+2*l16+1
                if (domask) {
                    const int rowloc = mi * 16 + quad * 4 + r;
                    if (2 * lane16 > rowloc) p0 = 0.f;
                    if (2 * lane16 + 1 > rowloc) p1 = 0.f;
                }
                bf16_t pb[2] = {(bf16_t)p0, (bf16_t)p1};
                *(unsigned int*)(wb + (mi * 16 + r) * LDA) =
                    *(const unsigned int*)pb;
            }
    };
    auto pv = [&]() {
        __builtin_amdgcn_s_setprio(1);
        o[0][0] = mfma16(pf0, vprev0, o[0][0]);
        o[0][1] = mfma16(pf0, vprev1, o[0][1]);
        o[1][0] = mfma16(pf1, vprev0, o[1][0]);
        o[1][1] = mfma16(pf1, vprev1, o[1][1]);
        ol[0] = mfma16(pf0, ones, ol[0]);
        ol[1] = mfma16(pf1, ones, ol[1]);
        __builtin_amdgcn_s_setprio(0);
    };

    const int nb = qt + 1;  // kv blocks (last = masked diagonal)

    // ---- iter 0: QK+exp+write buf0; V0 kept in regs; prefetch K1
    kc0 = *(const bf16x8*)(kp0);
    kc1 = *(const bf16x8*)(kp0 + HDIM);
    qk();
    vprev0 = *(const bf16x8*)(vp0);
    vprev1 = *(const bf16x8*)(vp1);
    if (nb > 1) {
        kc0 = *(const bf16x8*)(kp0 + 32 * HDIM);
        kc1 = *(const bf16x8*)(kp0 + 32 * HDIM + HDIM);
    }
    expw(wbase0, nb == 1);

    // ---- main loop i = 1..nb-2 (branch-free body)
    for (int i = 1; i < nb - 1; i++) {
        const int kv = i << 5;
        qk();  // K block i
        bf16x8 vc0 = *(const bf16x8*)(vp0 + kv);
        bf16x8 vc1 = *(const bf16x8*)(vp1 + kv);
        // branchless K prefetch (worst case reads 2KB past kbuf, inside d_out)
        bf16x8 kn0 = *(const bf16x8*)(kp0 + (kv + 32) * HDIM);
        bf16x8 kn1 = *(const bf16x8*)(kp0 + (kv + 32) * HDIM + HDIM);
        ldp(((i - 1) & 1) ? rbase1 : rbase0);  // issue BEFORE the writes
        expw((i & 1) ? wbase1 : wbase0, false);
        pv();  // P(i-1) x V(i-1), overlapped with exp(i)
        kc0 = kn0;
        kc1 = kn1;
        vprev0 = vc0;
        vprev1 = vc1;
    }

    // ---- peeled last iter (masked diagonal), nb >= 2
    if (nb > 1) {
        const int kv = (nb - 1) << 5;
        qk();  // K block nb-1 (prefetched)
        bf16x8 vc0 = *(const bf16x8*)(vp0 + kv);
        bf16x8 vc1 = *(const bf16x8*)(vp1 + kv);
        ldp(((nb - 2) & 1) ? rbase1 : rbase0);
        expw(((nb - 1) & 1) ? wbase1 : wbase0, true);
        pv();  // P(nb-2) x V(nb-2)
        vprev0 = vc0;
        vprev1 = vc1;
    }

    // ---- epilogue: last P tile
    ldp(((nb - 1) & 1) ? rbase1 : rbase0);
    pv();

    // ---- normalize + store: l = ol[mi][r] (replicated across lane16)
#pragma unroll
    for (int mi = 0; mi < 2; mi++)
#pragma unroll
        for (int r = 0; r < 4; r++) {
            float inv = 1.0f / ol[mi][r];
            int qi = q0 + mi * 16 + quad * 4 + r;
            bf16_t* ob = out + (b * SEQ + qi) * DIM + h * HDIM;
            ob[lane16] = (bf16_t)(o[mi][0][r] * inv);
            ob[16 + lane16] = (bf16_t)(o[mi][1][r] * inv);
        }
}

extern "C" void kernel_launch(void* const* d_in, const int* in_sizes, int n_in,
                              void* d_out, int out_size, void* d_ws, size_t ws_size,
                              hipStream_t stream) {
    // input order: x, mask, section_log_len, wq, wk, wv, wo, seq_scale
    // dtype model (verified): fp32 I/O, bf16 internal compute.
    const float* x = (const float*)d_in[0];
    const float* slen = (const float*)d_in[2];
    const float* wq = (const float*)d_in[3];
    const float* wk = (const float*)d_in[4];
    const float* wv = (const float*)d_in[5];
    const float* wo = (const float*)d_in[6];
    const float* ss = (const float*)d_in[7];

    const size_t ELEMS = (size_t)NB * SEQ * DIM;  // 4 Mi elems
    const size_t WELEMS = (size_t)DIM * DIM;      // 1 Mi elems
    // ws layout (bf16 elems), 32 MB:
    bf16_t* xb = (bf16_t*)d_ws;           // phase 1: bf16 x
    bf16_t* abuf = xb;                    // phase 2: attn out
    bf16_t* wqkvb = xb + ELEMS;           // packed [wq;wk;wv], N=3072
    bf16_t* wob = wqkvb + 3 * WELEMS;
    bf16_t* qbuf = wob + WELEMS;          // (B,H,S,HD), PRE-SCALED (incl log2e)
    bf16_t* vtbuf = qbuf + ELEMS;         // (B,H,HD,S)
    bf16_t* kbuf = (bf16_t*)d_out;        // 8 MB of 16 MB fp32 out (scratch)

    dim3 blk(256);
    cvt_f32_bf16<<<dim3(1024), blk, 0, stream>>>(
        x, xb, (int)ELEMS, wq, wqkvb, (int)WELEMS, wk, wqkvb + WELEMS,
        (int)WELEMS, wv, wqkvb + 2 * WELEMS, (int)WELEMS, wo, wob, (int)WELEMS);

    // QKV: 768 blocks (3/CU), XCD-swizzled, 3-deep pipelined K-loop, swizzled LDS
    gemm_pipe<1, 128><<<dim3(768), blk, 0, stream>>>(
        xb, wqkvb, nullptr, qbuf, kbuf, vtbuf, slen, ss);
    // attn: 1024 blocks, 1 wave per q-tile, software-pipelined P
    attn_fwd<<<dim3(NB * NH * (SEQ / 32) / 4), blk, 0, stream>>>(
        qbuf, kbuf, vtbuf, abuf);
    // out-proj: 512 blocks (2/CU), XCD-swizzled, 3-deep pipelined K-loop
    gemm_pipe<0, 64><<<dim3(512), blk, 0, stream>>>(
        abuf, wob, (float*)d_out, nullptr, nullptr, nullptr, nullptr, nullptr);
}